// Round 7
// baseline (226.149 us; speedup 1.0000x reference)
//
#include <hip/hip_runtime.h>
#include <math.h>

#define HH 1024
#define WW 1024
#define NPLANES 12              // B*C = 4*3
#define PLANE (HH * WW)
#define NTOT (NPLANES * PLANE)  // 12,582,912

#define TW 64                   // output tile width
#define TH 64                   // output tile height
#define HR 78                   // h-blurred rows needed = TH + 14
#define PITCH 68                // LDS row pitch (floats) — proven 0-conflict

typedef _Float16 h16;
typedef _Float16 h4 __attribute__((ext_vector_type(4)));

struct W15 { float w[15]; };

__device__ inline float chain1(float t, float gain, float gamma, float sb,
                               float hr, float br, float ct) {
    t = t * gain;
    t = __builtin_amdgcn_exp2f(gamma * __log2f(t));          // pow(t,gamma), t>=0
    float hi = __fdividef(1.0f, 1.0f + __expf((0.5f - t) * 10.0f));
    t = t + sb * (1.0f - hi) - hr * hi;
    t = fminf(fmaxf(t, 0.0f), 1.0f);
    t = ct * (t - 0.5f) + 0.5f + br;
    return fminf(fmaxf(t, 0.0f), 1.0f);
}

// 15-tap horizontal dot, 4 outputs, two accumulator trees per output
__device__ inline float4 hdot4(const float f[20], const W15& wk) {
    float4 o; float* po = (float*)&o;
#pragma unroll
    for (int j = 0; j < 4; ++j) {
        float a = 0.0f, b = 0.0f;
#pragma unroll
        for (int k = 0; k < 8; ++k)  a += wk.w[k] * f[j + 1 + k];
#pragma unroll
        for (int k = 8; k < 15; ++k) b += wk.w[k] * f[j + 1 + k];
        po[j] = a + b;
    }
    return o;
}

// ============ K1: pointwise chain, fp32 in -> fp16 out ========================
__global__ __launch_bounds__(256) void k_point(
    const float4* __restrict__ x, h4* __restrict__ o,
    const float* __restrict__ gains,
    const float* __restrict__ pg, const float* __restrict__ psb,
    const float* __restrict__ phr, const float* __restrict__ pbr,
    const float* __restrict__ pct)
{
    int i = blockIdx.x * blockDim.x + threadIdx.x;
    if (i >= NTOT / 4) return;
    int c = ((i * 4) / PLANE) % 3;           // PLANE % 4 == 0 -> uniform per float4
    float gain = gains[c];
    float gamma = *pg, sb = *psb, hr = *phr, br = *pbr, ct = *pct;

    float4 v = x[i];
    h4 hv;
    float* pv = (float*)&v;
#pragma unroll
    for (int j = 0; j < 4; ++j)
        hv[j] = (h16)chain1(pv[j], gain, gamma, sb, hr, br, ct);
    o[i] = hv;
}

// ---- h-blur phase shared by both blur kernels (fp16 source) ------------------
__device__ inline void hblur_stage(const h16* __restrict__ plane, float* __restrict__ hbl,
                                   int x0, int y0, int tid, bool edge, const W15& wk)
{
    const int cx = (tid & 15) * 4;       // 0..60
    const int r0 = tid >> 4;             // 0..15
    if (!edge) {
#pragma unroll
        for (int it = 0; it < 5; ++it) {
            int r = r0 + 16 * it;
            if (r < HR) {
                const h16* rp = plane + (size_t)(y0 - 7 + r) * WW + (x0 + cx - 8);
                float f[20];
#pragma unroll
                for (int m = 0; m < 5; ++m) {
                    h4 hv = *(const h4*)(rp + 4 * m);
#pragma unroll
                    for (int j = 0; j < 4; ++j) f[4 * m + j] = (float)hv[j];
                }
                *(float4*)&hbl[r * PITCH + cx] = hdot4(f, wk);
            }
        }
    } else {
        for (int it = 0; it < 5; ++it) {
            int r = r0 + 16 * it;
            if (r < HR) {
                int gy = y0 - 7 + r;
                float4 o;
                if (gy >= 0 && gy < HH) {
                    const h16* row = plane + (size_t)gy * WW;
                    int xb = x0 + cx - 8;
                    float f[20];
#pragma unroll
                    for (int m = 0; m < 20; ++m) {
                        int xx = xb + m;
                        f[m] = (xx >= 0 && xx < WW) ? (float)row[xx] : 0.0f;
                    }
                    o = hdot4(f, wk);
                } else {
                    o = make_float4(0.0f, 0.0f, 0.0f, 0.0f);
                }
                *(float4*)&hbl[r * PITCH + cx] = o;
            }
        }
    }
}

// ============ K2: blur(t0) + local contrast -> x2 (fp16 -> fp16) ==============
__global__ __launch_bounds__(256) void k_blur_lce(
    const h16* __restrict__ t0, h16* __restrict__ x2,
    const float* __restrict__ penh, W15 wk)
{
    __shared__ float hbl[HR * PITCH];    // 21.2 KB
    const int p   = blockIdx.z;
    const int x0  = blockIdx.x * TW;
    const int y0  = blockIdx.y * TH;
    const int tid = threadIdx.x;
    const h16* plane = t0 + (size_t)p * PLANE;
    const bool edge = (blockIdx.x == 0) || (blockIdx.x == WW / TW - 1) ||
                      (blockIdx.y == 0) || (blockIdx.y == HH / TH - 1);

    hblur_stage(plane, hbl, x0, y0, tid, edge, wk);
    __syncthreads();

    const int tx  = tid & 63;
    const int ty  = tid >> 6;
    const int ly0 = ty * 16;
    const int gx  = x0 + tx;
    const float e = *penh;

    float win[15];
#pragma unroll
    for (int k = 0; k < 15; ++k) win[k] = hbl[(ly0 + k) * PITCH + tx];

    h16* dstP = x2 + (size_t)p * PLANE;
#pragma unroll
    for (int j = 0; j < 16; ++j) {
        int y = y0 + ly0 + j;
        float a = 0.0f, b = 0.0f;
#pragma unroll
        for (int k = 0; k < 8; ++k)  a += wk.w[k] * win[k];
#pragma unroll
        for (int k = 8; k < 15; ++k) b += wk.w[k] * win[k];
        float lm = a + b;
        float c = (float)plane[(size_t)y * WW + gx];       // t0 center (L2-hot)
        dstP[(size_t)y * WW + gx] = (h16)((1.0f + e) * c - e * lm);
#pragma unroll
        for (int k = 0; k < 14; ++k) win[k] = win[k + 1];
        win[14] = hbl[(ly0 + j + 15) * PITCH + tx];
    }
}

// ============ K3: blur(x2) + softness + gradient mask + clip -> fp32 out ======
__global__ __launch_bounds__(256) void k_blur_final(
    const h16* __restrict__ x2, float* __restrict__ dst,
    const float* __restrict__ psoft, const float* __restrict__ pint,
    const float* __restrict__ prot, const float* __restrict__ phard, W15 wk)
{
    __shared__ float hbl[HR * PITCH];
    const int p   = blockIdx.z;
    const int x0  = blockIdx.x * TW;
    const int y0  = blockIdx.y * TH;
    const int tid = threadIdx.x;
    const h16* plane = x2 + (size_t)p * PLANE;
    const bool edge = (blockIdx.x == 0) || (blockIdx.x == WW / TW - 1) ||
                      (blockIdx.y == 0) || (blockIdx.y == HH / TH - 1);

    hblur_stage(plane, hbl, x0, y0, tid, edge, wk);
    __syncthreads();

    const int tx  = tid & 63;
    const int ty  = tid >> 6;
    const int ly0 = ty * 16;
    const int gx  = x0 + tx;

    const float s     = *psoft;
    const float inten = *pint;
    const float hard  = *phard;
    const float theta = (*prot) * 0.017453292519943295f;
    const float cth = __cosf(theta), sth = __sinf(theta);
    const float base = (-1.0f + 2.0f * (float)gx * (1.0f / (float)(WW - 1))) * cth;

    float win[15];
#pragma unroll
    for (int k = 0; k < 15; ++k) win[k] = hbl[(ly0 + k) * PITCH + tx];

    float* dstP = dst + (size_t)p * PLANE;
#pragma unroll
    for (int j = 0; j < 16; ++j) {
        int y = y0 + ly0 + j;
        float a = 0.0f, b = 0.0f;
#pragma unroll
        for (int k = 0; k < 8; ++k)  a += wk.w[k] * win[k];
#pragma unroll
        for (int k = 8; k < 15; ++k) b += wk.w[k] * win[k];
        float bl = a + b;
        float c = (float)plane[(size_t)y * WW + gx];       // x2 center (L2-hot)
        float v = s * bl + (1.0f - s) * c;
        float gyf = -1.0f + 2.0f * (float)y * (1.0f / (float)(HH - 1));
        float mask = __fdividef(1.0f, 1.0f + __expf(hard * (base + gyf * sth)));
        v = v * (1.0f - inten * mask);
        v = fminf(fmaxf(v, 0.0f), 1.0f);
        dstP[(size_t)y * WW + gx] = v;
#pragma unroll
        for (int k = 0; k < 14; ++k) win[k] = win[k + 1];
        win[14] = hbl[(ly0 + j + 15) * PITCH + tx];
    }
}

extern "C" void kernel_launch(void* const* d_in, const int* in_sizes, int n_in,
                              void* d_out, int out_size, void* d_ws, size_t ws_size,
                              hipStream_t stream)
{
    const float* x       = (const float*)d_in[0];
    const float* gains   = (const float*)d_in[1];
    const float* p_gamma = (const float*)d_in[2];
    const float* p_sb    = (const float*)d_in[3];
    const float* p_hr    = (const float*)d_in[4];
    const float* p_br    = (const float*)d_in[5];
    const float* p_ct    = (const float*)d_in[6];
    const float* p_enh   = (const float*)d_in[7];
    const float* p_soft  = (const float*)d_in[8];
    const float* p_int   = (const float*)d_in[9];
    const float* p_rot   = (const float*)d_in[10];
    const float* p_hard  = (const float*)d_in[11];

    h16* T0 = (h16*)d_ws;          // 25.2 MB
    h16* X2 = T0 + NTOT;           // 25.2 MB  (total 50.3 MB, same as before)
    float* OUT = (float*)d_out;

    W15 wk;
    {
        double g[15], sum = 0.0;
        for (int i = 0; i < 15; ++i) { double d = (double)(i - 7); g[i] = exp(-d * d / 18.0); sum += g[i]; }
        for (int i = 0; i < 15; ++i) wk.w[i] = (float)(g[i] / sum);
    }

    // K1: x -> T0 (fp16)
    k_point<<<dim3(NTOT / 4 / 256), dim3(256), 0, stream>>>(
        (const float4*)x, (h4*)T0, gains, p_gamma, p_sb, p_hr, p_br, p_ct);

    dim3 grid(WW / TW, HH / TH, NPLANES);   // 16 x 16 x 12
    // K2: T0 -> X2 (blur + local contrast, fp16->fp16)
    k_blur_lce<<<grid, dim3(256), 0, stream>>>(T0, X2, p_enh, wk);
    // K3: X2 -> OUT (blur + softness + gradient + clip, fp16->fp32)
    k_blur_final<<<grid, dim3(256), 0, stream>>>(X2, OUT, p_soft, p_int, p_rot, p_hard, wk);
}

// Round 8
// 190.160 us; speedup vs baseline: 1.1893x; 1.1893x over previous
//
#include <hip/hip_runtime.h>
#include <math.h>

#define HH 1024
#define WW 1024
#define NPLANES 12              // B*C = 4*3
#define PLANE (HH * WW)
#define NTOT (NPLANES * PLANE)  // 12,582,912

#define TW 64                   // output tile width
#define TH 64                   // output tile height
#define HR 78                   // h-blurred rows needed = TH + 14
#define PITCH 68                // LDS row pitch (floats) — proven 0-conflict

struct W15 { float w[15]; };

// zero-padded aligned float4 row load (x must be multiple of 4)
__device__ inline float4 ld4z(const float* __restrict__ row, int x) {
    if (x >= 0 && x + 3 < WW) return *(const float4*)(row + x);
    float4 r; float* p = (float*)&r;
#pragma unroll
    for (int j = 0; j < 4; ++j) { int xx = x + j; p[j] = (xx >= 0 && xx < WW) ? row[xx] : 0.0f; }
    return r;
}

__device__ inline float chain1(float t, float gain, float gamma, float sb,
                               float hr, float br, float ct) {
    t = t * gain;
    t = __builtin_amdgcn_exp2f(gamma * __log2f(t));          // pow(t,gamma), t>=0
    float hi = __fdividef(1.0f, 1.0f + __expf((0.5f - t) * 10.0f));
    t = t + sb * (1.0f - hi) - hr * hi;
    t = fminf(fmaxf(t, 0.0f), 1.0f);
    t = ct * (t - 0.5f) + 0.5f + br;
    return fminf(fmaxf(t, 0.0f), 1.0f);
}

// 15-tap horizontal dot, 4 outputs, two accumulator trees per output
__device__ inline float4 hdot4(const float f[20], const W15& wk) {
    float4 o; float* po = (float*)&o;
#pragma unroll
    for (int j = 0; j < 4; ++j) {
        float a = 0.0f, b = 0.0f;
#pragma unroll
        for (int k = 0; k < 8; ++k)  a += wk.w[k] * f[j + 1 + k];
#pragma unroll
        for (int k = 8; k < 15; ++k) b += wk.w[k] * f[j + 1 + k];
        po[j] = a + b;
    }
    return o;
}

// ============ K1: pointwise chain, fp32 -> fp32 ===============================
__global__ __launch_bounds__(256) void k_point(
    const float4* __restrict__ x, float4* __restrict__ o,
    const float* __restrict__ gains,
    const float* __restrict__ pg, const float* __restrict__ psb,
    const float* __restrict__ phr, const float* __restrict__ pbr,
    const float* __restrict__ pct)
{
    int i = blockIdx.x * blockDim.x + threadIdx.x;
    if (i >= NTOT / 4) return;
    int c = ((i * 4) / PLANE) % 3;           // PLANE % 4 == 0 -> uniform per float4
    float gain = gains[c];
    float gamma = *pg, sb = *psb, hr = *phr, br = *pbr, ct = *pct;

    float4 v = x[i];
    float* pv = (float*)&v;
#pragma unroll
    for (int j = 0; j < 4; ++j)
        pv[j] = chain1(pv[j], gain, gamma, sb, hr, br, ct);
    o[i] = v;
}

// ---- h-blur phase shared by both blur kernels (fp32 source, fast path) -------
__device__ inline void hblur_stage(const float* __restrict__ plane, float* __restrict__ hbl,
                                   int x0, int y0, int tid, bool edge, const W15& wk)
{
    const int cx = (tid & 15) * 4;       // 0..60
    const int r0 = tid >> 4;             // 0..15
    if (!edge) {
#pragma unroll
        for (int it = 0; it < 5; ++it) {
            int r = r0 + 16 * it;
            if (r < HR) {
                const float* rp = plane + (size_t)(y0 - 7 + r) * WW + (x0 + cx - 8);
                float f[20];
                *(float4*)&f[0]  = *(const float4*)(rp);
                *(float4*)&f[4]  = *(const float4*)(rp + 4);
                *(float4*)&f[8]  = *(const float4*)(rp + 8);
                *(float4*)&f[12] = *(const float4*)(rp + 12);
                *(float4*)&f[16] = *(const float4*)(rp + 16);
                *(float4*)&hbl[r * PITCH + cx] = hdot4(f, wk);
            }
        }
    } else {
        for (int it = 0; it < 5; ++it) {
            int r = r0 + 16 * it;
            if (r < HR) {
                int gy = y0 - 7 + r;
                float4 o;
                if (gy >= 0 && gy < HH) {
                    const float* row = plane + (size_t)gy * WW;
                    int xb = x0 + cx - 8;
                    float f[20];
                    *(float4*)&f[0]  = ld4z(row, xb);
                    *(float4*)&f[4]  = ld4z(row, xb + 4);
                    *(float4*)&f[8]  = ld4z(row, xb + 8);
                    *(float4*)&f[12] = ld4z(row, xb + 12);
                    *(float4*)&f[16] = ld4z(row, xb + 16);
                    o = hdot4(f, wk);
                } else {
                    o = make_float4(0.0f, 0.0f, 0.0f, 0.0f);
                }
                *(float4*)&hbl[r * PITCH + cx] = o;
            }
        }
    }
}

// ============ K2: blur(t0) + local contrast -> x2 =============================
__global__ __launch_bounds__(256) void k_blur_lce(
    const float* __restrict__ t0, float* __restrict__ x2,
    const float* __restrict__ penh, W15 wk)
{
    __shared__ float hbl[HR * PITCH];    // 21.2 KB
    const int p   = blockIdx.z;
    const int x0  = blockIdx.x * TW;
    const int y0  = blockIdx.y * TH;
    const int tid = threadIdx.x;
    const float* plane = t0 + (size_t)p * PLANE;
    const bool edge = (blockIdx.x == 0) || (blockIdx.x == WW / TW - 1) ||
                      (blockIdx.y == 0) || (blockIdx.y == HH / TH - 1);

    hblur_stage(plane, hbl, x0, y0, tid, edge, wk);
    __syncthreads();

    const int tx  = tid & 63;
    const int ty  = tid >> 6;
    const int ly0 = ty * 16;
    const int gx  = x0 + tx;
    const float e = *penh;

    float win[15];
#pragma unroll
    for (int k = 0; k < 15; ++k) win[k] = hbl[(ly0 + k) * PITCH + tx];

    float* dstP = x2 + (size_t)p * PLANE;
#pragma unroll
    for (int j = 0; j < 16; ++j) {
        int y = y0 + ly0 + j;
        float a = 0.0f, b = 0.0f;
#pragma unroll
        for (int k = 0; k < 8; ++k)  a += wk.w[k] * win[k];
#pragma unroll
        for (int k = 8; k < 15; ++k) b += wk.w[k] * win[k];
        float lm = a + b;
        float c = plane[(size_t)y * WW + gx];              // t0 center (L2-hot)
        dstP[(size_t)y * WW + gx] = (1.0f + e) * c - e * lm;
#pragma unroll
        for (int k = 0; k < 14; ++k) win[k] = win[k + 1];
        win[14] = hbl[(ly0 + j + 15) * PITCH + tx];
    }
}

// ============ K3: blur(x2) + softness + gradient mask + clip -> out ===========
__global__ __launch_bounds__(256) void k_blur_final(
    const float* __restrict__ x2, float* __restrict__ dst,
    const float* __restrict__ psoft, const float* __restrict__ pint,
    const float* __restrict__ prot, const float* __restrict__ phard, W15 wk)
{
    __shared__ float hbl[HR * PITCH];
    const int p   = blockIdx.z;
    const int x0  = blockIdx.x * TW;
    const int y0  = blockIdx.y * TH;
    const int tid = threadIdx.x;
    const float* plane = x2 + (size_t)p * PLANE;
    const bool edge = (blockIdx.x == 0) || (blockIdx.x == WW / TW - 1) ||
                      (blockIdx.y == 0) || (blockIdx.y == HH / TH - 1);

    hblur_stage(plane, hbl, x0, y0, tid, edge, wk);
    __syncthreads();

    const int tx  = tid & 63;
    const int ty  = tid >> 6;
    const int ly0 = ty * 16;
    const int gx  = x0 + tx;

    const float s     = *psoft;
    const float inten = *pint;
    const float hard  = *phard;
    const float theta = (*prot) * 0.017453292519943295f;
    const float cth = __cosf(theta), sth = __sinf(theta);
    const float base = (-1.0f + 2.0f * (float)gx * (1.0f / (float)(WW - 1))) * cth;

    float win[15];
#pragma unroll
    for (int k = 0; k < 15; ++k) win[k] = hbl[(ly0 + k) * PITCH + tx];

    float* dstP = dst + (size_t)p * PLANE;
#pragma unroll
    for (int j = 0; j < 16; ++j) {
        int y = y0 + ly0 + j;
        float a = 0.0f, b = 0.0f;
#pragma unroll
        for (int k = 0; k < 8; ++k)  a += wk.w[k] * win[k];
#pragma unroll
        for (int k = 8; k < 15; ++k) b += wk.w[k] * win[k];
        float bl = a + b;
        float c = plane[(size_t)y * WW + gx];              // x2 center (L2-hot)
        float v = s * bl + (1.0f - s) * c;
        float gyf = -1.0f + 2.0f * (float)y * (1.0f / (float)(HH - 1));
        float mask = __fdividef(1.0f, 1.0f + __expf(hard * (base + gyf * sth)));
        v = v * (1.0f - inten * mask);
        v = fminf(fmaxf(v, 0.0f), 1.0f);
        dstP[(size_t)y * WW + gx] = v;
#pragma unroll
        for (int k = 0; k < 14; ++k) win[k] = win[k + 1];
        win[14] = hbl[(ly0 + j + 15) * PITCH + tx];
    }
}

extern "C" void kernel_launch(void* const* d_in, const int* in_sizes, int n_in,
                              void* d_out, int out_size, void* d_ws, size_t ws_size,
                              hipStream_t stream)
{
    const float* x       = (const float*)d_in[0];
    const float* gains   = (const float*)d_in[1];
    const float* p_gamma = (const float*)d_in[2];
    const float* p_sb    = (const float*)d_in[3];
    const float* p_hr    = (const float*)d_in[4];
    const float* p_br    = (const float*)d_in[5];
    const float* p_ct    = (const float*)d_in[6];
    const float* p_enh   = (const float*)d_in[7];
    const float* p_soft  = (const float*)d_in[8];
    const float* p_int   = (const float*)d_in[9];
    const float* p_rot   = (const float*)d_in[10];
    const float* p_hard  = (const float*)d_in[11];

    float* T0  = (float*)d_out;   // t0 lives in d_out (K3 overwrites it at the end)
    float* X2  = (float*)d_ws;    // x2 intermediate (50.3 MB)
    float* OUT = (float*)d_out;

    W15 wk;
    {
        double g[15], sum = 0.0;
        for (int i = 0; i < 15; ++i) { double d = (double)(i - 7); g[i] = exp(-d * d / 18.0); sum += g[i]; }
        for (int i = 0; i < 15; ++i) wk.w[i] = (float)(g[i] / sum);
    }

    // K1: x -> T0
    k_point<<<dim3(NTOT / 4 / 256), dim3(256), 0, stream>>>(
        (const float4*)x, (float4*)T0, gains, p_gamma, p_sb, p_hr, p_br, p_ct);

    dim3 grid(WW / TW, HH / TH, NPLANES);   // 16 x 16 x 12
    // K2: T0 -> X2 (blur + local contrast)
    k_blur_lce<<<grid, dim3(256), 0, stream>>>(T0, X2, p_enh, wk);
    // K3: X2 -> OUT (blur + softness + gradient + clip)
    k_blur_final<<<grid, dim3(256), 0, stream>>>(X2, OUT, p_soft, p_int, p_rot, p_hard, wk);
}

// Round 9
// 186.801 us; speedup vs baseline: 1.2106x; 1.0180x over previous
//
#include <hip/hip_runtime.h>
#include <math.h>

#define HH 1024
#define WW 1024
#define NPLANES 12              // B*C = 4*3
#define PLANE (HH * WW)
#define NTOT (NPLANES * PLANE)  // 12,582,912

#define TW 64                   // output tile width
#define TH 64                   // output tile height
#define HR 78                   // h-blurred rows needed = TH + 14
#define PITCH 68                // LDS row pitch (floats) — proven 0-conflict

struct W15 { float w[15]; };

// zero-padded aligned float4 row load (x must be multiple of 4)
__device__ inline float4 ld4z(const float* __restrict__ row, int x) {
    if (x >= 0 && x + 3 < WW) return *(const float4*)(row + x);
    float4 r; float* p = (float*)&r;
#pragma unroll
    for (int j = 0; j < 4; ++j) { int xx = x + j; p[j] = (xx >= 0 && xx < WW) ? row[xx] : 0.0f; }
    return r;
}

__device__ inline float chain1(float t, float gain, float gamma, float sb,
                               float hr, float br, float ct) {
    t = t * gain;
    t = __builtin_amdgcn_exp2f(gamma * __log2f(t));          // pow(t,gamma), t>=0
    float hi = __fdividef(1.0f, 1.0f + __expf((0.5f - t) * 10.0f));
    t = t + sb * (1.0f - hi) - hr * hi;
    t = fminf(fmaxf(t, 0.0f), 1.0f);
    t = ct * (t - 0.5f) + 0.5f + br;
    return fminf(fmaxf(t, 0.0f), 1.0f);
}

// 15-tap horizontal dot, 4 outputs, two accumulator trees per output
__device__ inline float4 hdot4(const float* f, const W15& wk) {
    float4 o; float* po = (float*)&o;
#pragma unroll
    for (int j = 0; j < 4; ++j) {
        float a = 0.0f, b = 0.0f;
#pragma unroll
        for (int k = 0; k < 8; ++k)  a += wk.w[k] * f[j + 1 + k];
#pragma unroll
        for (int k = 8; k < 15; ++k) b += wk.w[k] * f[j + 1 + k];
        po[j] = a + b;
    }
    return o;
}

// ============ K1: pointwise chain, fp32 -> fp32 ===============================
__global__ __launch_bounds__(256) void k_point(
    const float4* __restrict__ x, float4* __restrict__ o,
    const float* __restrict__ gains,
    const float* __restrict__ pg, const float* __restrict__ psb,
    const float* __restrict__ phr, const float* __restrict__ pbr,
    const float* __restrict__ pct)
{
    int i = blockIdx.x * blockDim.x + threadIdx.x;
    if (i >= NTOT / 4) return;
    int c = ((i * 4) / PLANE) % 3;           // PLANE % 4 == 0 -> uniform per float4
    float gain = gains[c];
    float gamma = *pg, sb = *psb, hr = *phr, br = *pbr, ct = *pct;

    float4 v = x[i];
    float* pv = (float*)&v;
#pragma unroll
    for (int j = 0; j < 4; ++j)
        pv[j] = chain1(pv[j], gain, gamma, sb, hr, br, ct);
    o[i] = v;
}

// ---- XCD-aware tile remap: same-XCD (mod-8) blocks cover contiguous region ---
__device__ inline void tile_map(int& p, int& x0, int& y0, bool& edge) {
    int L = (blockIdx.z * gridDim.y + blockIdx.y) * gridDim.x + blockIdx.x; // 0..3071
    int xcd = L & 7;
    int t   = L >> 3;                 // 0..383
    int g   = xcd * 384 + t;          // contiguous 1.5-plane region per XCD
    p = g >> 8;                       // /256 tiles per plane
    int w  = g & 255;
    int ty = w >> 4, tx = w & 15;
    x0 = tx * TW; y0 = ty * TH;
    edge = (tx == 0) || (tx == 15) || (ty == 0) || (ty == 15);
}

__device__ inline void ldrow20(float* f, const float* rp) {
    *(float4*)&f[0]  = *(const float4*)(rp);
    *(float4*)&f[4]  = *(const float4*)(rp + 4);
    *(float4*)&f[8]  = *(const float4*)(rp + 8);
    *(float4*)&f[12] = *(const float4*)(rp + 12);
    *(float4*)&f[16] = *(const float4*)(rp + 16);
}

// ---- h-blur phase: fast path software-pipelined 1-ahead ----------------------
__device__ inline void hblur_stage(const float* __restrict__ plane, float* __restrict__ hbl,
                                   int x0, int y0, int tid, bool edge, const W15& wk)
{
    const int cx = (tid & 15) * 4;       // 0..60
    const int r0 = tid >> 4;             // 0..15
    if (!edge) {
        const float* base = plane + (size_t)(y0 - 7) * WW + (x0 + cx - 8);
        float f[2][20];
        ldrow20(f[0], base + (size_t)r0 * WW);                 // prologue load
#pragma unroll
        for (int it = 0; it < 5; ++it) {
            int r  = r0 + 16 * it;
            int rn = r + 16;
            if (it < 4 && rn < HR)
                ldrow20(f[(it + 1) & 1], base + (size_t)rn * WW);  // prefetch next
            if (r < HR)
                *(float4*)&hbl[r * PITCH + cx] = hdot4(f[it & 1], wk);
        }
    } else {
        for (int it = 0; it < 5; ++it) {
            int r = r0 + 16 * it;
            if (r < HR) {
                int gy = y0 - 7 + r;
                float4 o;
                if (gy >= 0 && gy < HH) {
                    const float* row = plane + (size_t)gy * WW;
                    int xb = x0 + cx - 8;
                    float f[20];
                    *(float4*)&f[0]  = ld4z(row, xb);
                    *(float4*)&f[4]  = ld4z(row, xb + 4);
                    *(float4*)&f[8]  = ld4z(row, xb + 8);
                    *(float4*)&f[12] = ld4z(row, xb + 12);
                    *(float4*)&f[16] = ld4z(row, xb + 16);
                    o = hdot4(f, wk);
                } else {
                    o = make_float4(0.0f, 0.0f, 0.0f, 0.0f);
                }
                *(float4*)&hbl[r * PITCH + cx] = o;
            }
        }
    }
}

// ============ K2: blur(t0) + local contrast -> x2 =============================
__global__ __launch_bounds__(256) void k_blur_lce(
    const float* __restrict__ t0, float* __restrict__ x2,
    const float* __restrict__ penh, W15 wk)
{
    __shared__ float hbl[HR * PITCH];    // 21.2 KB
    int p, x0, y0; bool edge;
    tile_map(p, x0, y0, edge);
    const int tid = threadIdx.x;
    const float* plane = t0 + (size_t)p * PLANE;

    hblur_stage(plane, hbl, x0, y0, tid, edge, wk);
    __syncthreads();

    const int tx  = tid & 63;
    const int ty  = tid >> 6;
    const int ly0 = ty * 16;
    const int gx  = x0 + tx;
    const float e = *penh;

    // preload all 16 centers (coalesced, 16 outstanding)
    float cc[16];
#pragma unroll
    for (int j = 0; j < 16; ++j) cc[j] = plane[(size_t)(y0 + ly0 + j) * WW + gx];

    float win[15];
#pragma unroll
    for (int k = 0; k < 15; ++k) win[k] = hbl[(ly0 + k) * PITCH + tx];

    float* dstP = x2 + (size_t)p * PLANE;
#pragma unroll
    for (int j = 0; j < 16; ++j) {
        int y = y0 + ly0 + j;
        float a = 0.0f, b = 0.0f;
#pragma unroll
        for (int k = 0; k < 8; ++k)  a += wk.w[k] * win[k];
#pragma unroll
        for (int k = 8; k < 15; ++k) b += wk.w[k] * win[k];
        float lm = a + b;
        dstP[(size_t)y * WW + gx] = (1.0f + e) * cc[j] - e * lm;
#pragma unroll
        for (int k = 0; k < 14; ++k) win[k] = win[k + 1];
        win[14] = hbl[(ly0 + j + 15) * PITCH + tx];
    }
}

// ============ K3: blur(x2) + softness + gradient mask + clip -> out ===========
__global__ __launch_bounds__(256) void k_blur_final(
    const float* __restrict__ x2, float* __restrict__ dst,
    const float* __restrict__ psoft, const float* __restrict__ pint,
    const float* __restrict__ prot, const float* __restrict__ phard, W15 wk)
{
    __shared__ float hbl[HR * PITCH];
    int p, x0, y0; bool edge;
    tile_map(p, x0, y0, edge);
    const int tid = threadIdx.x;
    const float* plane = x2 + (size_t)p * PLANE;

    hblur_stage(plane, hbl, x0, y0, tid, edge, wk);
    __syncthreads();

    const int tx  = tid & 63;
    const int ty  = tid >> 6;
    const int ly0 = ty * 16;
    const int gx  = x0 + tx;

    const float s     = *psoft;
    const float inten = *pint;
    const float hard  = *phard;
    const float theta = (*prot) * 0.017453292519943295f;
    const float cth = __cosf(theta), sth = __sinf(theta);
    const float base = (-1.0f + 2.0f * (float)gx * (1.0f / (float)(WW - 1))) * cth;

    float cc[16];
#pragma unroll
    for (int j = 0; j < 16; ++j) cc[j] = plane[(size_t)(y0 + ly0 + j) * WW + gx];

    float win[15];
#pragma unroll
    for (int k = 0; k < 15; ++k) win[k] = hbl[(ly0 + k) * PITCH + tx];

    float* dstP = dst + (size_t)p * PLANE;
#pragma unroll
    for (int j = 0; j < 16; ++j) {
        int y = y0 + ly0 + j;
        float a = 0.0f, b = 0.0f;
#pragma unroll
        for (int k = 0; k < 8; ++k)  a += wk.w[k] * win[k];
#pragma unroll
        for (int k = 8; k < 15; ++k) b += wk.w[k] * win[k];
        float bl = a + b;
        float v = s * bl + (1.0f - s) * cc[j];
        float gyf = -1.0f + 2.0f * (float)y * (1.0f / (float)(HH - 1));
        float mask = __fdividef(1.0f, 1.0f + __expf(hard * (base + gyf * sth)));
        v = v * (1.0f - inten * mask);
        v = fminf(fmaxf(v, 0.0f), 1.0f);
        dstP[(size_t)y * WW + gx] = v;
#pragma unroll
        for (int k = 0; k < 14; ++k) win[k] = win[k + 1];
        win[14] = hbl[(ly0 + j + 15) * PITCH + tx];
    }
}

extern "C" void kernel_launch(void* const* d_in, const int* in_sizes, int n_in,
                              void* d_out, int out_size, void* d_ws, size_t ws_size,
                              hipStream_t stream)
{
    const float* x       = (const float*)d_in[0];
    const float* gains   = (const float*)d_in[1];
    const float* p_gamma = (const float*)d_in[2];
    const float* p_sb    = (const float*)d_in[3];
    const float* p_hr    = (const float*)d_in[4];
    const float* p_br    = (const float*)d_in[5];
    const float* p_ct    = (const float*)d_in[6];
    const float* p_enh   = (const float*)d_in[7];
    const float* p_soft  = (const float*)d_in[8];
    const float* p_int   = (const float*)d_in[9];
    const float* p_rot   = (const float*)d_in[10];
    const float* p_hard  = (const float*)d_in[11];

    float* T0  = (float*)d_out;   // t0 lives in d_out (K3 overwrites it at the end)
    float* X2  = (float*)d_ws;    // x2 intermediate (50.3 MB)
    float* OUT = (float*)d_out;

    W15 wk;
    {
        double g[15], sum = 0.0;
        for (int i = 0; i < 15; ++i) { double d = (double)(i - 7); g[i] = exp(-d * d / 18.0); sum += g[i]; }
        for (int i = 0; i < 15; ++i) wk.w[i] = (float)(g[i] / sum);
    }

    // K1: x -> T0
    k_point<<<dim3(NTOT / 4 / 256), dim3(256), 0, stream>>>(
        (const float4*)x, (float4*)T0, gains, p_gamma, p_sb, p_hr, p_br, p_ct);

    dim3 grid(WW / TW, HH / TH, NPLANES);   // 16 x 16 x 12 (remapped in-kernel)
    // K2: T0 -> X2 (blur + local contrast)
    k_blur_lce<<<grid, dim3(256), 0, stream>>>(T0, X2, p_enh, wk);
    // K3: X2 -> OUT (blur + softness + gradient + clip)
    k_blur_final<<<grid, dim3(256), 0, stream>>>(X2, OUT, p_soft, p_int, p_rot, p_hard, wk);
}